// Round 2
// baseline (1251.883 us; speedup 1.0000x reference)
//
#include <hip/hip_runtime.h>

#define B_N   262144
#define D_IN  256
#define H_DIM 64

typedef __attribute__((ext_vector_type(8))) short bf16x8;   // 8 bf16 = 4 VGPRs
typedef __attribute__((ext_vector_type(4))) float f32x4;    // MFMA 16x16 accumulator

__device__ __forceinline__ float b2f(unsigned short u) {
    union { unsigned int i; float f; } c; c.i = ((unsigned int)u) << 16; return c.f;
}
__device__ __forceinline__ unsigned short f2b(float f) {
    union { float f; unsigned int i; } c; c.f = f;
    unsigned int u = c.i;
    return (unsigned short)((u + 0x7FFFu + ((u >> 16) & 1u)) >> 16);
}
__device__ __forceinline__ float sigm(float x)   { return 1.0f / (1.0f + __expf(-x)); }
__device__ __forceinline__ float tanh_f(float x) { return 1.0f - 2.0f / (__expf(2.0f * x) + 1.0f); }

// ---- dtype-agnostic access helpers (f32 flag is wave-uniform) ----
__device__ __forceinline__ bf16x8 load8(const void* p, size_t i, bool f32) {
    if (f32) {
        const float* q = (const float*)p + i;
        float4 a = *(const float4*)q;
        float4 b = *(const float4*)(q + 4);
        bf16x8 v;
        v[0] = f2b(a.x); v[1] = f2b(a.y); v[2] = f2b(a.z); v[3] = f2b(a.w);
        v[4] = f2b(b.x); v[5] = f2b(b.y); v[6] = f2b(b.z); v[7] = f2b(b.w);
        return v;
    }
    return *(const bf16x8*)((const unsigned short*)p + i);
}
__device__ __forceinline__ float ld1(const void* p, size_t i, bool f32) {
    return f32 ? ((const float*)p)[i] : b2f(((const unsigned short*)p)[i]);
}
__device__ __forceinline__ void st1(void* p, size_t i, bool f32, float v) {
    if (f32) ((float*)p)[i] = v;
    else     ((unsigned short*)p)[i] = f2b(v);
}
__device__ __forceinline__ void st8(void* p, size_t i, bool f32, const unsigned short* s8) {
    if (f32) {
        float* q = (float*)p + i;
        float4 a, b;
        a.x = b2f(s8[0]); a.y = b2f(s8[1]); a.z = b2f(s8[2]); a.w = b2f(s8[3]);
        b.x = b2f(s8[4]); b.y = b2f(s8[5]); b.z = b2f(s8[6]); b.w = b2f(s8[7]);
        *(float4*)q = a; *(float4*)(q + 4) = b;
    } else {
        *(bf16x8*)((unsigned short*)p + i) = *(const bf16x8*)s8;
    }
}

// Sniff obs dtype: fp32 N(0,1) data viewed as ushorts has ~1/256 of (even-index)
// shorts with bf16-exponent 0xFF; genuine bf16 N(0,1) data has none.
__global__ void sniff_kernel(const unsigned short* __restrict__ obs, int* __restrict__ flag) {
    __shared__ int total;
    if (threadIdx.x == 0) total = 0;
    __syncthreads();
    int cnt = 0;
    for (int i = threadIdx.x; i < 16384; i += 256) {
        int e = (obs[i] >> 7) & 0xFF;
        cnt += (e == 0xFF) ? 1 : 0;
    }
    atomicAdd(&total, cnt);
    __syncthreads();
    if (threadIdx.x == 0) *flag = (total > 4) ? 1 : 0;   // 1 = fp32 buffers
}

__global__ __launch_bounds__(256, 4)
void gru_critic_kernel(
    const void* __restrict__ obs,
    const void* __restrict__ h1,
    const void* __restrict__ h2,
    const int*  __restrict__ mask,
    const void* __restrict__ Wfc1_1, const void* __restrict__ bfc1_1,
    const void* __restrict__ wih_1,  const void* __restrict__ whh_1,
    const void* __restrict__ bih_1,  const void* __restrict__ bhh_1,
    const void* __restrict__ Wfc2_1, const void* __restrict__ bfc2_1,
    const void* __restrict__ Wfc1_2, const void* __restrict__ bfc1_2,
    const void* __restrict__ wih_2,  const void* __restrict__ whh_2,
    const void* __restrict__ bih_2,  const void* __restrict__ bhh_2,
    const void* __restrict__ Wfc2_2, const void* __restrict__ bfc2_2,
    const int*  __restrict__ flag,
    void* __restrict__ out)
{
    __shared__ __align__(16) unsigned short lds[4 * 2 * 32 * 72];  // 36,864 B

    const bool f32 = (*flag != 0);
    const int lane = threadIdx.x & 63;
    const int wave = threadIdx.x >> 6;
    const int lm   = lane & 15;        // m (A) or n (B) within a 16-tile
    const int lq   = lane >> 4;        // quad 0..3
    const int lk   = lq * 8;           // k offset within a 32-chunk
    const int row0 = blockIdx.x * 128 + wave * 32;

    unsigned short* xt = &lds[wave * 4608];   // x tile   [32][72]
    unsigned short* nt = xt + 2304;           // newh tile[32][72]

    const void* Wfc1s[2] = {Wfc1_1, Wfc1_2};
    const void* bfc1s[2] = {bfc1_1, bfc1_2};
    const void* wihs[2]  = {wih_1,  wih_2};
    const void* whhs[2]  = {whh_1,  whh_2};
    const void* bihs[2]  = {bih_1,  bih_2};
    const void* bhhs[2]  = {bhh_1,  bhh_2};
    const void* Wfc2s[2] = {Wfc2_1, Wfc2_2};
    const void* bfc2s[2] = {bfc2_1, bfc2_2};
    const void* hss[2]   = {h1, h2};

    for (int s = 0; s < 2; ++s) {
        const void* Wfc1 = Wfc1s[s];
        const void* bfc1 = bfc1s[s];
        const void* wih  = wihs[s];
        const void* whh  = whhs[s];
        const void* bih  = bihs[s];
        const void* bhh  = bhhs[s];
        const void* Wfc2 = Wfc2s[s];
        const void* bfc2 = bfc2s[s];
        const void* h    = hss[s];

        // ---------- Phase 1: x = tanh(obs @ Wfc1^T + bfc1) ----------
        f32x4 acc[2][4];
        #pragma unroll
        for (int a = 0; a < 2; ++a)
            #pragma unroll
            for (int b = 0; b < 4; ++b)
                acc[a][b] = (f32x4){0.f, 0.f, 0.f, 0.f};

        #pragma unroll
        for (int k = 0; k < D_IN; k += 32) {
            bf16x8 a0 = load8(obs, (size_t)(row0 +      lm) * D_IN + k + lk, f32);
            bf16x8 a1 = load8(obs, (size_t)(row0 + 16 + lm) * D_IN + k + lk, f32);
            #pragma unroll
            for (int n = 0; n < 4; ++n) {
                bf16x8 b = load8(Wfc1, (size_t)(n * 16 + lm) * D_IN + k + lk, f32);
                acc[0][n] = __builtin_amdgcn_mfma_f32_16x16x32_bf16(a0, b, acc[0][n], 0, 0, 0);
                acc[1][n] = __builtin_amdgcn_mfma_f32_16x16x32_bf16(a1, b, acc[1][n], 0, 0, 0);
            }
        }
        // C-layout (col = lane&15, row = quad*4 + reg) -> row-major LDS tile
        #pragma unroll
        for (int m2 = 0; m2 < 2; ++m2) {
            #pragma unroll
            for (int n = 0; n < 4; ++n) {
                const int col  = n * 16 + lm;
                const float bi = ld1(bfc1, col, f32);
                const int rb   = m2 * 16 + lq * 4;
                #pragma unroll
                for (int r = 0; r < 4; ++r)
                    xt[(rb + r) * 72 + col] = f2b(tanh_f(acc[m2][n][r] + bi));
            }
        }
        __syncthreads();

        // ---------- Phase 2: GRU gates ----------
        #pragma unroll
        for (int m2 = 0; m2 < 2; ++m2) {
            bf16x8 ax[2], ah[2];
            #pragma unroll
            for (int kk = 0; kk < 2; ++kk) {
                ax[kk] = *(const bf16x8*)&xt[(m2 * 16 + lm) * 72 + kk * 32 + lk];
                ah[kk] = load8(h, (size_t)(row0 + m2 * 16 + lm) * H_DIM + kk * 32 + lk, f32);
            }
            const int rowb = row0 + m2 * 16 + lq * 4;
            int mk[4];
            #pragma unroll
            for (int r = 0; r < 4; ++r) mk[r] = mask[rowb + r];

            #pragma unroll
            for (int j = 0; j < 4; ++j) {   // 16-col chunk of H
                f32x4 air = {0,0,0,0}, aiz = {0,0,0,0}, ain = {0,0,0,0};
                f32x4 ahr = {0,0,0,0}, ahz = {0,0,0,0}, ahn = {0,0,0,0};
                #pragma unroll
                for (int kk = 0; kk < 2; ++kk) {
                    const int ko = kk * 32 + lk;
                    const size_t rw = (size_t)(j * 16 + lm) * H_DIM + ko;
                    bf16x8 br = load8(wih, rw, f32);
                    bf16x8 bz = load8(wih,  64 * H_DIM + rw, f32);
                    bf16x8 bn = load8(wih, 128 * H_DIM + rw, f32);
                    air = __builtin_amdgcn_mfma_f32_16x16x32_bf16(ax[kk], br, air, 0, 0, 0);
                    aiz = __builtin_amdgcn_mfma_f32_16x16x32_bf16(ax[kk], bz, aiz, 0, 0, 0);
                    ain = __builtin_amdgcn_mfma_f32_16x16x32_bf16(ax[kk], bn, ain, 0, 0, 0);
                    br = load8(whh, rw, f32);
                    bz = load8(whh,  64 * H_DIM + rw, f32);
                    bn = load8(whh, 128 * H_DIM + rw, f32);
                    ahr = __builtin_amdgcn_mfma_f32_16x16x32_bf16(ah[kk], br, ahr, 0, 0, 0);
                    ahz = __builtin_amdgcn_mfma_f32_16x16x32_bf16(ah[kk], bz, ahz, 0, 0, 0);
                    ahn = __builtin_amdgcn_mfma_f32_16x16x32_bf16(ah[kk], bn, ahn, 0, 0, 0);
                }
                const int col = j * 16 + lm;
                const float brz  = ld1(bih, col, f32)       + ld1(bhh, col, f32);
                const float bzz  = ld1(bih, 64 + col, f32)  + ld1(bhh, 64 + col, f32);
                const float bin_ = ld1(bih, 128 + col, f32);
                const float bhn_ = ld1(bhh, 128 + col, f32);
                #pragma unroll
                for (int r = 0; r < 4; ++r) {
                    const float hv = ld1(h, (size_t)(rowb + r) * H_DIM + col, f32);
                    const float rg = sigm(air[r] + ahr[r] + brz);
                    const float zg = sigm(aiz[r] + ahz[r] + bzz);
                    const float ng = tanh_f(ain[r] + bin_ + rg * (ahn[r] + bhn_));
                    const float nh = mk[r] ? ((1.0f - zg) * ng + zg * hv) : hv;
                    nt[(m2 * 16 + lq * 4 + r) * 72 + col] = f2b(nh);
                }
            }
        }
        __syncthreads();

        // ---------- Phase 3: store new_h + value head ----------
        #pragma unroll
        for (int it = 0; it < 4; ++it) {
            const int chunk = it * 64 + lane;      // 256 chunks of 8 elems = 32x64 tile
            const int r = chunk >> 3;
            const int c = (chunk & 7) * 8;
            const size_t oidx = 2 * (size_t)B_N + (size_t)s * B_N * H_DIM
                              + (size_t)(row0 + r) * H_DIM + c;
            st8(out, oidx, f32, &nt[r * 72 + c]);
        }
        {
            const int r  = lane >> 1;
            const int hf = lane & 1;
            float sum = 0.f;
            #pragma unroll
            for (int q = 0; q < 4; ++q) {
                bf16x8 hv = *(const bf16x8*)&nt[r * 72 + hf * 32 + q * 8];
                #pragma unroll
                for (int e = 0; e < 8; ++e)
                    sum += b2f((unsigned short)hv[e]) * ld1(Wfc2, hf * 32 + q * 8 + e, f32);
            }
            sum += __shfl_xor(sum, 1);
            if (hf == 0)
                st1(out, (size_t)s * B_N + row0 + r, f32, sum + ld1(bfc2, 0, f32));
        }
        __syncthreads();   // xt/nt reused by next stream
    }
}

extern "C" void kernel_launch(void* const* d_in, const int* in_sizes, int n_in,
                              void* d_out, int out_size, void* d_ws, size_t ws_size,
                              hipStream_t stream) {
    int* flag = (int*)d_ws;
    hipLaunchKernelGGL(sniff_kernel, dim3(1), dim3(256), 0, stream,
                       (const unsigned short*)d_in[0], flag);
    dim3 grid(B_N / 128), block(256);
    hipLaunchKernelGGL(gru_critic_kernel, grid, block, 0, stream,
        d_in[0],              // global_obs
        d_in[1],              // h1
        d_in[2],              // h2
        (const int*)d_in[3],  // active_masks
        d_in[4],  d_in[5],  d_in[6],  d_in[7],  d_in[8],  d_in[9],
        d_in[10], d_in[11],
        d_in[12], d_in[13], d_in[14], d_in[15], d_in[16], d_in[17],
        d_in[18], d_in[19],
        flag, d_out);
}